// Round 1
// baseline (161.615 us; speedup 1.0000x reference)
//
#include <hip/hip_runtime.h>

// Problem constants (from reference setup_inputs)
#define BB 32
#define MM 2048
#define DD 1024
#define KK 5120   // C*D = 5*1024

// Workspace layout (floats):
//   a      : [B][D]  @ 0          (32768)
//   logits : [B][M]  @ 32768      (65536)
//   w      : [B][M]  @ 98304      (65536)

// ---------------- Kernel A: a[b,d] = sum_k P[d,k] * y[b,k] ----------------
// Grid: D/8 = 128 blocks of 256 threads (4 waves). Each block owns 8 d-rows,
// wave w owns 8 batches. Register tile 8x8 per thread; P read exactly once.
__global__ __launch_bounds__(256) void k_a(const float* __restrict__ P,
                                           const float* __restrict__ y,
                                           float* __restrict__ a) {
    const int d0 = blockIdx.x * 8;
    const int wave = threadIdx.x >> 6;
    const int lane = threadIdx.x & 63;
    const int b0 = wave * 8;

    float acc[8][8];
#pragma unroll
    for (int i = 0; i < 8; ++i)
#pragma unroll
        for (int j = 0; j < 8; ++j) acc[i][j] = 0.f;

    for (int i = 0; i < KK / 64; ++i) {
        const int k = lane + i * 64;
        float pv[8], yv[8];
#pragma unroll
        for (int dd = 0; dd < 8; ++dd) pv[dd] = P[(size_t)(d0 + dd) * KK + k];
#pragma unroll
        for (int bb = 0; bb < 8; ++bb) yv[bb] = y[(size_t)(b0 + bb) * KK + k];
#pragma unroll
        for (int dd = 0; dd < 8; ++dd)
#pragma unroll
            for (int bb = 0; bb < 8; ++bb)
                acc[dd][bb] = fmaf(pv[dd], yv[bb], acc[dd][bb]);
    }

#pragma unroll
    for (int dd = 0; dd < 8; ++dd)
#pragma unroll
        for (int bb = 0; bb < 8; ++bb) {
            float v = acc[dd][bb];
#pragma unroll
            for (int off = 32; off; off >>= 1) v += __shfl_xor(v, off, 64);
            if (lane == 0) a[(size_t)(b0 + bb) * DD + (d0 + dd)] = v;
        }
}

// ------------- Kernel B: logits[b,m] = dot(x[b,m,:], a[b,:]) --------------
// Grid: (M/4, B); block 256 threads = 4 waves, one row per wave.
__global__ __launch_bounds__(256) void k_logits(const float* __restrict__ x,
                                                const float* __restrict__ a,
                                                float* __restrict__ logits) {
    const int b = blockIdx.y;
    const int m0 = blockIdx.x * 4;
    __shared__ float sa[DD];
    {
        const float4* src = (const float4*)(a + (size_t)b * DD);
        ((float4*)sa)[threadIdx.x] = src[threadIdx.x];
    }
    __syncthreads();

    const int wave = threadIdx.x >> 6;
    const int lane = threadIdx.x & 63;
    const int m = m0 + wave;
    const float* row = x + ((size_t)b * MM + m) * DD;

    float sum = 0.f;
#pragma unroll
    for (int q = 0; q < 4; ++q) {
        const int d = lane * 4 + q * 256;
        const float4 xv = *(const float4*)(row + d);
        const float4 av = *(const float4*)(sa + d);
        sum = fmaf(xv.x, av.x, sum);
        sum = fmaf(xv.y, av.y, sum);
        sum = fmaf(xv.z, av.z, sum);
        sum = fmaf(xv.w, av.w, sum);
    }
#pragma unroll
    for (int off = 32; off; off >>= 1) sum += __shfl_xor(sum, off, 64);
    if (lane == 0) logits[(size_t)b * MM + m] = sum;
}

// -------- Kernel C: per-batch softmax over M, then window weights w -------
// w[b,j] = 0.5 * (p[j-1]+p[j]+p[j+1]+p[j+2]) with clamped indices; w[M-1]=0.
__global__ __launch_bounds__(256) void k_softmax_w(const float* __restrict__ logits,
                                                   float* __restrict__ w) {
    const int b = blockIdx.x;
    __shared__ float p[MM];
    __shared__ float red[8];
    const int t = threadIdx.x;
    const int lane = t & 63, wave = t >> 6;

    float mx = -INFINITY;
    for (int m = t; m < MM; m += 256) {
        const float v = logits[(size_t)b * MM + m];
        p[m] = v;
        mx = fmaxf(mx, v);
    }
#pragma unroll
    for (int off = 32; off; off >>= 1) mx = fmaxf(mx, __shfl_xor(mx, off, 64));
    if (lane == 0) red[wave] = mx;
    __syncthreads();
    mx = fmaxf(fmaxf(red[0], red[1]), fmaxf(red[2], red[3]));

    float s = 0.f;
    for (int m = t; m < MM; m += 256) {
        const float e = __expf(p[m] - mx);
        p[m] = e;
        s += e;
    }
#pragma unroll
    for (int off = 32; off; off >>= 1) s += __shfl_xor(s, off, 64);
    if (lane == 0) red[4 + wave] = s;
    __syncthreads();
    s = red[4] + red[5] + red[6] + red[7];

    const float inv = 0.5f / s;  // folds the 1/Q = 1/2 factor
    for (int j = t; j < MM; j += 256) {
        float wv;
        if (j == MM - 1) {
            wv = 0.f;  // last row is in no window (e is clipped to M-1, end-exclusive)
        } else {
            float acc = p[j];
            if (j >= 1) acc += p[j - 1];
            if (j + 1 <= MM - 1) acc += p[j + 1];
            if (j + 2 <= MM - 1) acc += p[j + 2];
            wv = acc * inv;
        }
        w[(size_t)b * MM + j] = wv;
    }
}

// ----------------------- zero-init d_out (poisoned) -----------------------
__global__ void k_zero(float* __restrict__ out) {
    out[blockIdx.x * 256 + threadIdx.x] = 0.f;
}

// ------------- Kernel D: enc[b,d] = sum_j w[b,j] * x[b,j,d] ---------------
// Grid: (JS=32, B). Block covers full D via float4/thread; 64 rows per block;
// partial sums combined with atomicAdd.
__global__ __launch_bounds__(256) void k_enc(const float* __restrict__ x,
                                             const float* __restrict__ w,
                                             float* __restrict__ out) {
    const int b = blockIdx.y;
    const int j0 = blockIdx.x * (MM / 32);
    const int d = threadIdx.x * 4;

    float4 acc = {0.f, 0.f, 0.f, 0.f};
    const float* xb = x + (size_t)b * MM * DD + d;
    const float* wb = w + (size_t)b * MM;

    for (int j = j0; j < j0 + (MM / 32); ++j) {
        const float wv = wb[j];
        const float4 xv = *(const float4*)(xb + (size_t)j * DD);
        acc.x = fmaf(wv, xv.x, acc.x);
        acc.y = fmaf(wv, xv.y, acc.y);
        acc.z = fmaf(wv, xv.z, acc.z);
        acc.w = fmaf(wv, xv.w, acc.w);
    }

    float* o = out + (size_t)b * DD + d;
    atomicAdd(o + 0, acc.x);
    atomicAdd(o + 1, acc.y);
    atomicAdd(o + 2, acc.z);
    atomicAdd(o + 3, acc.w);
}

extern "C" void kernel_launch(void* const* d_in, const int* in_sizes, int n_in,
                              void* d_out, int out_size, void* d_ws, size_t ws_size,
                              hipStream_t stream) {
    (void)in_sizes; (void)n_in; (void)out_size; (void)ws_size;
    const float* x = (const float*)d_in[0];   // [B, M, D]
    const float* y = (const float*)d_in[1];   // [B, C*D, 1]
    const float* P = (const float*)d_in[2];   // [D, C*D]
    float* out = (float*)d_out;               // [B, D]

    float* ws = (float*)d_ws;
    float* a      = ws;                 // B*D
    float* logits = ws + 32768;         // B*M
    float* w      = ws + 32768 + 65536; // B*M

    k_a<<<dim3(DD / 8), dim3(256), 0, stream>>>(P, y, a);
    k_logits<<<dim3(MM / 4, BB), dim3(256), 0, stream>>>(x, a, logits);
    k_softmax_w<<<dim3(BB), dim3(256), 0, stream>>>(logits, w);
    k_zero<<<dim3((BB * DD) / 256), dim3(256), 0, stream>>>(out);
    k_enc<<<dim3(32, BB), dim3(256), 0, stream>>>(x, w, out);
}

// Round 2
// 135.252 us; speedup vs baseline: 1.1949x; 1.1949x over previous
//
#include <hip/hip_runtime.h>

// Problem constants (from reference setup_inputs)
#define BB 32
#define MM 2048
#define DD 1024
#define KK 5120   // C*D = 5*1024

// Workspace layout (floats):
//   a      : [B][D]  @ 0          (32768)
//   logits : [B][M]  @ 32768      (65536)
//   w      : [B][M]  @ 98304      (65536)

// ---------------- Kernel A: a[b,d] = sum_k P[d,k] * y[b,k] ----------------
// Also zero-inits d_out (poisoned by harness) so k_enc can atomicAdd.
// Grid: D/8 = 128 blocks of 256 threads (4 waves). Block owns 8 d-rows,
// wave owns 8 batches; float4 loads (16 B/lane); P read exactly once.
__global__ __launch_bounds__(256) void k_a(const float* __restrict__ P,
                                           const float* __restrict__ y,
                                           float* __restrict__ a,
                                           float* __restrict__ out) {
    // zero out[32*1024] : 128 blocks x 256 threads
    out[blockIdx.x * 256 + threadIdx.x] = 0.f;

    const int d0 = blockIdx.x * 8;
    const int wave = threadIdx.x >> 6;
    const int lane = threadIdx.x & 63;
    const int b0 = wave * 8;

    float acc[8][8];
#pragma unroll
    for (int i = 0; i < 8; ++i)
#pragma unroll
        for (int j = 0; j < 8; ++j) acc[i][j] = 0.f;

    // KK/4 = 1280 float4 per row; 1280/64 lanes = 20 iterations
    for (int i = 0; i < 20; ++i) {
        const int k4 = lane + i * 64;
        float4 pv[8], yv[8];
#pragma unroll
        for (int dd = 0; dd < 8; ++dd)
            pv[dd] = ((const float4*)(P + (size_t)(d0 + dd) * KK))[k4];
#pragma unroll
        for (int bb = 0; bb < 8; ++bb)
            yv[bb] = ((const float4*)(y + (size_t)(b0 + bb) * KK))[k4];
#pragma unroll
        for (int dd = 0; dd < 8; ++dd)
#pragma unroll
            for (int bb = 0; bb < 8; ++bb) {
                acc[dd][bb] = fmaf(pv[dd].x, yv[bb].x, acc[dd][bb]);
                acc[dd][bb] = fmaf(pv[dd].y, yv[bb].y, acc[dd][bb]);
                acc[dd][bb] = fmaf(pv[dd].z, yv[bb].z, acc[dd][bb]);
                acc[dd][bb] = fmaf(pv[dd].w, yv[bb].w, acc[dd][bb]);
            }
    }

#pragma unroll
    for (int dd = 0; dd < 8; ++dd)
#pragma unroll
        for (int bb = 0; bb < 8; ++bb) {
            float v = acc[dd][bb];
#pragma unroll
            for (int off = 32; off; off >>= 1) v += __shfl_xor(v, off, 64);
            if (lane == 0) a[(size_t)(b0 + bb) * DD + (d0 + dd)] = v;
        }
}

// ------------- Kernel B: logits[b,m] = dot(x[b,m,:], a[b,:]) --------------
// Grid: (M/8, B); block 256 = 4 waves; each wave owns 2 rows (more MLP).
// a is read directly from global (4 KB/batch, L1/L2-hot across blocks).
__global__ __launch_bounds__(256) void k_logits(const float* __restrict__ x,
                                                const float* __restrict__ a,
                                                float* __restrict__ logits) {
    const int b = blockIdx.y;
    const int wave = threadIdx.x >> 6;
    const int lane = threadIdx.x & 63;
    const int m = blockIdx.x * 8 + wave * 2;

    const float* ab = a + (size_t)b * DD;
    const float* row0 = x + ((size_t)b * MM + m) * DD;
    const float* row1 = row0 + DD;

    float s0 = 0.f, s1 = 0.f;
#pragma unroll
    for (int q = 0; q < 4; ++q) {
        const int d = lane * 4 + q * 256;
        const float4 av = *(const float4*)(ab + d);
        const float4 x0 = *(const float4*)(row0 + d);
        const float4 x1 = *(const float4*)(row1 + d);
        s0 = fmaf(x0.x, av.x, s0); s0 = fmaf(x0.y, av.y, s0);
        s0 = fmaf(x0.z, av.z, s0); s0 = fmaf(x0.w, av.w, s0);
        s1 = fmaf(x1.x, av.x, s1); s1 = fmaf(x1.y, av.y, s1);
        s1 = fmaf(x1.z, av.z, s1); s1 = fmaf(x1.w, av.w, s1);
    }
#pragma unroll
    for (int off = 32; off; off >>= 1) {
        s0 += __shfl_xor(s0, off, 64);
        s1 += __shfl_xor(s1, off, 64);
    }
    if (lane == 0) {
        logits[(size_t)b * MM + m] = s0;
        logits[(size_t)b * MM + m + 1] = s1;
    }
}

// -------- Kernel C: per-batch softmax over M, then window weights w -------
// w[b,j] = 0.5 * (p[j-1]+p[j]+p[j+1]+p[j+2]) with clamped indices; w[M-1]=0.
__global__ __launch_bounds__(256) void k_softmax_w(const float* __restrict__ logits,
                                                   float* __restrict__ w) {
    const int b = blockIdx.x;
    __shared__ float p[MM];
    __shared__ float red[8];
    const int t = threadIdx.x;
    const int lane = t & 63, wave = t >> 6;

    float mx = -INFINITY;
    for (int m = t; m < MM; m += 256) {
        const float v = logits[(size_t)b * MM + m];
        p[m] = v;
        mx = fmaxf(mx, v);
    }
#pragma unroll
    for (int off = 32; off; off >>= 1) mx = fmaxf(mx, __shfl_xor(mx, off, 64));
    if (lane == 0) red[wave] = mx;
    __syncthreads();
    mx = fmaxf(fmaxf(red[0], red[1]), fmaxf(red[2], red[3]));

    float s = 0.f;
    for (int m = t; m < MM; m += 256) {
        const float e = __expf(p[m] - mx);
        p[m] = e;
        s += e;
    }
#pragma unroll
    for (int off = 32; off; off >>= 1) s += __shfl_xor(s, off, 64);
    if (lane == 0) red[4 + wave] = s;
    __syncthreads();
    s = red[4] + red[5] + red[6] + red[7];

    const float inv = 0.5f / s;  // folds the 1/Q = 1/2 factor
    for (int j = t; j < MM; j += 256) {
        float wv;
        if (j == MM - 1) {
            wv = 0.f;  // last row is in no window (e clipped to M-1, end-exclusive)
        } else {
            float acc = p[j];
            if (j >= 1) acc += p[j - 1];
            if (j + 1 <= MM - 1) acc += p[j + 1];
            if (j + 2 <= MM - 1) acc += p[j + 2];
            wv = acc * inv;
        }
        w[(size_t)b * MM + j] = wv;
    }
}

// ------------- Kernel D: enc[b,d] = sum_j w[b,j] * x[b,j,d] ---------------
// REVERSE global read order: k_logits streamed x ascending, so the tail of
// x is L3-resident. Low block ids here read the highest addresses first,
// and iterate j descending — eviction chases behind the reversed read.
__global__ __launch_bounds__(256) void k_enc(const float* __restrict__ x,
                                             const float* __restrict__ w,
                                             float* __restrict__ out) {
    const int b = (BB - 1) - blockIdx.y;
    const int chunk = 31 - blockIdx.x;
    const int j0 = chunk * (MM / 32);
    const int d = threadIdx.x * 4;

    float4 acc0 = {0.f, 0.f, 0.f, 0.f};
    float4 acc1 = {0.f, 0.f, 0.f, 0.f};
    const float* xb = x + (size_t)b * MM * DD + d;
    const float* wb = w + (size_t)b * MM;

    for (int j = j0 + (MM / 32) - 1; j >= j0; j -= 2) {
        const float w0 = wb[j];
        const float w1 = wb[j - 1];
        const float4 x0 = *(const float4*)(xb + (size_t)j * DD);
        const float4 x1 = *(const float4*)(xb + (size_t)(j - 1) * DD);
        acc0.x = fmaf(w0, x0.x, acc0.x); acc0.y = fmaf(w0, x0.y, acc0.y);
        acc0.z = fmaf(w0, x0.z, acc0.z); acc0.w = fmaf(w0, x0.w, acc0.w);
        acc1.x = fmaf(w1, x1.x, acc1.x); acc1.y = fmaf(w1, x1.y, acc1.y);
        acc1.z = fmaf(w1, x1.z, acc1.z); acc1.w = fmaf(w1, x1.w, acc1.w);
    }

    float* o = out + (size_t)b * DD + d;
    atomicAdd(o + 0, acc0.x + acc1.x);
    atomicAdd(o + 1, acc0.y + acc1.y);
    atomicAdd(o + 2, acc0.z + acc1.z);
    atomicAdd(o + 3, acc0.w + acc1.w);
}

extern "C" void kernel_launch(void* const* d_in, const int* in_sizes, int n_in,
                              void* d_out, int out_size, void* d_ws, size_t ws_size,
                              hipStream_t stream) {
    (void)in_sizes; (void)n_in; (void)out_size; (void)ws_size;
    const float* x = (const float*)d_in[0];   // [B, M, D]
    const float* y = (const float*)d_in[1];   // [B, C*D, 1]
    const float* P = (const float*)d_in[2];   // [D, C*D]
    float* out = (float*)d_out;               // [B, D]

    float* ws = (float*)d_ws;
    float* a      = ws;                 // B*D
    float* logits = ws + 32768;         // B*M
    float* w      = ws + 32768 + 65536; // B*M

    k_a<<<dim3(DD / 8), dim3(256), 0, stream>>>(P, y, a, out);
    k_logits<<<dim3(MM / 8, BB), dim3(256), 0, stream>>>(x, a, logits);
    k_softmax_w<<<dim3(BB), dim3(256), 0, stream>>>(logits, w);
    k_enc<<<dim3(32, BB), dim3(256), 0, stream>>>(x, w, out);
}